// Round 1
// baseline (112.847 us; speedup 1.0000x reference)
//
#include <hip/hip_runtime.h>

// Problem constants (from reference): x is (B, C, H, W) fp32.
constexpr int Bn = 32;
constexpr int Cn = 256;
constexpr int Hn = 96;
constexpr int Wn = 48;
constexpr int Nn = Hn * Wn;       // 4608 spatial positions
constexpr int N4 = Nn / 4;        // 1152 float4 per (b,c) row
constexpr float BN_EPS = 1e-5f;

// ---------------------------------------------------------------------------
// Pass 1: per (b, n) compute g/theta/phi channel dots over C.
//   - store theta[b,n] to workspace
//   - accumulate s[b] = sum_n phi*g via one atomicAdd per block
// Block = 64 threads (1 wave), each lane owns one float4 (4 n's).
// Grid = B * 18 blocks (18 * 64 * 4 = 4608 = N).
// ---------------------------------------------------------------------------
__global__ __launch_bounds__(64) void pass1_kernel(
    const float* __restrict__ x,
    const float* __restrict__ g_w, const float* __restrict__ g_b,
    const float* __restrict__ theta_w, const float* __restrict__ theta_b,
    const float* __restrict__ phi_w, const float* __restrict__ phi_b,
    float* __restrict__ theta_out,   // B * N floats
    float* __restrict__ s_out)       // B floats (pre-zeroed)
{
    __shared__ float wg[Cn], wt[Cn], wp[Cn];
    const int lane = threadIdx.x;
    #pragma unroll
    for (int i = lane; i < Cn; i += 64) {
        wg[i] = g_w[i];
        wt[i] = theta_w[i];
        wp[i] = phi_w[i];
    }
    __syncthreads();

    const int bx = blockIdx.x;
    const int b  = bx / 18;
    const int n4 = (bx % 18) * 64 + lane;   // 0..1151

    const float4* xb = reinterpret_cast<const float4*>(x)
                     + (size_t)b * (size_t)(Cn * N4) + n4;

    float4 ag = {0.f, 0.f, 0.f, 0.f};
    float4 at = {0.f, 0.f, 0.f, 0.f};
    float4 ap = {0.f, 0.f, 0.f, 0.f};

    #pragma unroll 16
    for (int c = 0; c < Cn; ++c) {
        const float4 xv = xb[(size_t)c * N4];
        const float cg = wg[c], ct = wt[c], cp = wp[c];
        ag.x = fmaf(cg, xv.x, ag.x);
        ag.y = fmaf(cg, xv.y, ag.y);
        ag.z = fmaf(cg, xv.z, ag.z);
        ag.w = fmaf(cg, xv.w, ag.w);
        at.x = fmaf(ct, xv.x, at.x);
        at.y = fmaf(ct, xv.y, at.y);
        at.z = fmaf(ct, xv.z, at.z);
        at.w = fmaf(ct, xv.w, at.w);
        ap.x = fmaf(cp, xv.x, ap.x);
        ap.y = fmaf(cp, xv.y, ap.y);
        ap.z = fmaf(cp, xv.z, ap.z);
        ap.w = fmaf(cp, xv.w, ap.w);
    }

    const float gb = g_b[0], tb = theta_b[0], pb = phi_b[0];

    // theta (store for pass 2)
    float4 th;
    th.x = at.x + tb; th.y = at.y + tb; th.z = at.z + tb; th.w = at.w + tb;
    reinterpret_cast<float4*>(theta_out)[(size_t)b * N4 + n4] = th;

    // phi * g, 4 elements per lane
    float p = (ag.x + gb) * (ap.x + pb)
            + (ag.y + gb) * (ap.y + pb)
            + (ag.z + gb) * (ap.z + pb)
            + (ag.w + gb) * (ap.w + pb);

    // wave (=block) reduction over 64 lanes
    #pragma unroll
    for (int off = 32; off > 0; off >>= 1)
        p += __shfl_down(p, off);

    if (lane == 0)
        atomicAdd(&s_out[b], p);
}

// ---------------------------------------------------------------------------
// Pass 2: elementwise epilogue, grid-stride over float4 elements.
//   out = (theta[b,n] * s[b]/N) * (W_w[c]*inv_std[c])
//         + ((W_b[c]-bn_mean[c])*inv_std[c] + bn_beta[c]) + x
// ---------------------------------------------------------------------------
__global__ __launch_bounds__(256) void pass2_kernel(
    const float* __restrict__ x,
    const float* __restrict__ theta_buf,
    const float* __restrict__ s_buf,
    const float* __restrict__ W_w, const float* __restrict__ W_b,
    const float* __restrict__ bn_gamma, const float* __restrict__ bn_beta,
    const float* __restrict__ bn_mean, const float* __restrict__ bn_var,
    float* __restrict__ out)
{
    constexpr int total4 = Bn * Cn * N4;    // 9,437,184
    const int stride = gridDim.x * blockDim.x;
    const float invN = 1.0f / (float)Nn;

    for (int idx = blockIdx.x * blockDim.x + threadIdx.x;
         idx < total4; idx += stride) {
        const int b   = idx / (Cn * N4);
        const int rem = idx - b * (Cn * N4);
        const int c   = rem / N4;
        const int n4  = rem - c * N4;

        const float inv_std = bn_gamma[c] * rsqrtf(bn_var[c] + BN_EPS);
        const float a = W_w[c] * inv_std;
        const float d = fmaf(W_b[c] - bn_mean[c], inv_std, bn_beta[c]);
        const float sb = s_buf[b] * invN;

        const float4 th = reinterpret_cast<const float4*>(theta_buf)[b * N4 + n4];
        const float4 xv = reinterpret_cast<const float4*>(x)[idx];

        float4 o;
        o.x = fmaf(th.x * sb, a, d) + xv.x;
        o.y = fmaf(th.y * sb, a, d) + xv.y;
        o.z = fmaf(th.z * sb, a, d) + xv.z;
        o.w = fmaf(th.w * sb, a, d) + xv.w;

        reinterpret_cast<float4*>(out)[idx] = o;
    }
}

extern "C" void kernel_launch(void* const* d_in, const int* in_sizes, int n_in,
                              void* d_out, int out_size, void* d_ws, size_t ws_size,
                              hipStream_t stream) {
    const float* x        = (const float*)d_in[0];
    const float* g_w      = (const float*)d_in[1];
    const float* g_b      = (const float*)d_in[2];
    const float* theta_w  = (const float*)d_in[3];
    const float* theta_b  = (const float*)d_in[4];
    const float* phi_w    = (const float*)d_in[5];
    const float* phi_b    = (const float*)d_in[6];
    const float* W_w      = (const float*)d_in[7];
    const float* W_b      = (const float*)d_in[8];
    const float* bn_gamma = (const float*)d_in[9];
    const float* bn_beta  = (const float*)d_in[10];
    const float* bn_mean  = (const float*)d_in[11];
    const float* bn_var   = (const float*)d_in[12];

    float* out = (float*)d_out;

    // Workspace layout: theta (B*N floats), then s (B floats)
    float* theta_buf = (float*)d_ws;
    float* s_buf     = (float*)((char*)d_ws + (size_t)Bn * Nn * sizeof(float));

    // zero the s accumulator each call (ws is NOT re-poisoned between replays)
    hipMemsetAsync(s_buf, 0, Bn * sizeof(float), stream);

    pass1_kernel<<<Bn * 18, 64, 0, stream>>>(
        x, g_w, g_b, theta_w, theta_b, phi_w, phi_b, theta_buf, s_buf);

    pass2_kernel<<<2048, 256, 0, stream>>>(
        x, theta_buf, s_buf, W_w, W_b, bn_gamma, bn_beta, bn_mean, bn_var, out);
}

// Round 2
// 83.072 us; speedup vs baseline: 1.3584x; 1.3584x over previous
//
#include <hip/hip_runtime.h>

// Problem constants (from reference): x is (B, C, H, W) fp32.
constexpr int Bn = 32;
constexpr int Cn = 256;
constexpr int Hn = 96;
constexpr int Wn = 48;
constexpr int Nn = Hn * Wn;       // 4608 spatial positions
constexpr int N4 = Nn / 4;        // 1152 float4 per (b,c) row
constexpr float BN_EPS = 1e-5f;

// ---------------------------------------------------------------------------
// Pass 1: per (b, n) compute g/theta/phi channel dots over C.
//   Block = 512 threads = 8 waves. Each wave covers 32 channels for the
//   same 64 float4 n-positions; LDS reduction combines the 8 partials.
//   Grid = B * 18 blocks (18 * 64 * 4 = 4608 = N) -> 4608 waves = 18/CU.
//   - store theta[b,n] to workspace
//   - accumulate s[b] = sum_n phi*g via one atomicAdd per block
// ---------------------------------------------------------------------------
__global__ __launch_bounds__(512) void pass1_kernel(
    const float* __restrict__ x,
    const float* __restrict__ g_w, const float* __restrict__ g_b,
    const float* __restrict__ theta_w, const float* __restrict__ theta_b,
    const float* __restrict__ phi_w, const float* __restrict__ phi_b,
    float* __restrict__ theta_out,   // B * N floats
    float* __restrict__ s_out)       // B floats (pre-zeroed)
{
    __shared__ float wg[Cn], wt[Cn], wp[Cn];
    __shared__ float4 red[3][8][64];   // 24 KiB cross-wave partials

    const int tid  = threadIdx.x;
    const int lane = tid & 63;
    const int wave = tid >> 6;

    if (tid < Cn) {
        wg[tid] = g_w[tid];
        wt[tid] = theta_w[tid];
        wp[tid] = phi_w[tid];
    }
    __syncthreads();

    const int bx = blockIdx.x;
    const int b  = bx / 18;
    const int n4 = (bx % 18) * 64 + lane;   // 0..1151

    const float4* xb = reinterpret_cast<const float4*>(x)
                     + (size_t)b * (size_t)(Cn * N4) + n4;

    float4 ag = {0.f, 0.f, 0.f, 0.f};
    float4 at = {0.f, 0.f, 0.f, 0.f};
    float4 ap = {0.f, 0.f, 0.f, 0.f};

    const int c0 = wave * 32;
    #pragma unroll 8
    for (int cc = 0; cc < 32; ++cc) {
        const int c = c0 + cc;
        const float4 xv = xb[(size_t)c * N4];
        const float cg = wg[c], ct = wt[c], cp = wp[c];
        ag.x = fmaf(cg, xv.x, ag.x);
        ag.y = fmaf(cg, xv.y, ag.y);
        ag.z = fmaf(cg, xv.z, ag.z);
        ag.w = fmaf(cg, xv.w, ag.w);
        at.x = fmaf(ct, xv.x, at.x);
        at.y = fmaf(ct, xv.y, at.y);
        at.z = fmaf(ct, xv.z, at.z);
        at.w = fmaf(ct, xv.w, at.w);
        ap.x = fmaf(cp, xv.x, ap.x);
        ap.y = fmaf(cp, xv.y, ap.y);
        ap.z = fmaf(cp, xv.z, ap.z);
        ap.w = fmaf(cp, xv.w, ap.w);
    }

    red[0][wave][lane] = ag;
    red[1][wave][lane] = at;
    red[2][wave][lane] = ap;
    __syncthreads();

    if (wave == 0) {
        float4 sg = red[0][0][lane];
        float4 st = red[1][0][lane];
        float4 sp = red[2][0][lane];
        #pragma unroll
        for (int w = 1; w < 8; ++w) {
            const float4 rg = red[0][w][lane];
            const float4 rt = red[1][w][lane];
            const float4 rp = red[2][w][lane];
            sg.x += rg.x; sg.y += rg.y; sg.z += rg.z; sg.w += rg.w;
            st.x += rt.x; st.y += rt.y; st.z += rt.z; st.w += rt.w;
            sp.x += rp.x; sp.y += rp.y; sp.z += rp.z; sp.w += rp.w;
        }

        const float gb = g_b[0], tb = theta_b[0], pb = phi_b[0];

        // theta (store for pass 2)
        float4 th;
        th.x = st.x + tb; th.y = st.y + tb; th.z = st.z + tb; th.w = st.w + tb;
        reinterpret_cast<float4*>(theta_out)[(size_t)b * N4 + n4] = th;

        // phi * g, 4 elements per lane
        float p = (sg.x + gb) * (sp.x + pb)
                + (sg.y + gb) * (sp.y + pb)
                + (sg.z + gb) * (sp.z + pb)
                + (sg.w + gb) * (sp.w + pb);

        // wave reduction over 64 lanes
        #pragma unroll
        for (int off = 32; off > 0; off >>= 1)
            p += __shfl_down(p, off);

        if (lane == 0)
            atomicAdd(&s_out[b], p);
    }
}

// ---------------------------------------------------------------------------
// Pass 2: elementwise epilogue, grid-stride over float4 elements.
//   out = (theta[b,n] * s[b]/N) * (W_w[c]*inv_std[c])
//         + ((W_b[c]-bn_mean[c])*inv_std[c] + bn_beta[c]) + x
// ---------------------------------------------------------------------------
__global__ __launch_bounds__(256) void pass2_kernel(
    const float* __restrict__ x,
    const float* __restrict__ theta_buf,
    const float* __restrict__ s_buf,
    const float* __restrict__ W_w, const float* __restrict__ W_b,
    const float* __restrict__ bn_gamma, const float* __restrict__ bn_beta,
    const float* __restrict__ bn_mean, const float* __restrict__ bn_var,
    float* __restrict__ out)
{
    constexpr int total4 = Bn * Cn * N4;    // 9,437,184
    const int stride = gridDim.x * blockDim.x;
    const float invN = 1.0f / (float)Nn;

    for (int idx = blockIdx.x * blockDim.x + threadIdx.x;
         idx < total4; idx += stride) {
        const int b   = idx / (Cn * N4);
        const int rem = idx - b * (Cn * N4);
        const int c   = rem / N4;
        const int n4  = rem - c * N4;

        const float inv_std = bn_gamma[c] * rsqrtf(bn_var[c] + BN_EPS);
        const float a = W_w[c] * inv_std;
        const float d = fmaf(W_b[c] - bn_mean[c], inv_std, bn_beta[c]);
        const float sb = s_buf[b] * invN;

        const float4 th = reinterpret_cast<const float4*>(theta_buf)[b * N4 + n4];
        const float4 xv = reinterpret_cast<const float4*>(x)[idx];

        float4 o;
        o.x = fmaf(th.x * sb, a, d) + xv.x;
        o.y = fmaf(th.y * sb, a, d) + xv.y;
        o.z = fmaf(th.z * sb, a, d) + xv.z;
        o.w = fmaf(th.w * sb, a, d) + xv.w;

        reinterpret_cast<float4*>(out)[idx] = o;
    }
}

extern "C" void kernel_launch(void* const* d_in, const int* in_sizes, int n_in,
                              void* d_out, int out_size, void* d_ws, size_t ws_size,
                              hipStream_t stream) {
    const float* x        = (const float*)d_in[0];
    const float* g_w      = (const float*)d_in[1];
    const float* g_b      = (const float*)d_in[2];
    const float* theta_w  = (const float*)d_in[3];
    const float* theta_b  = (const float*)d_in[4];
    const float* phi_w    = (const float*)d_in[5];
    const float* phi_b    = (const float*)d_in[6];
    const float* W_w      = (const float*)d_in[7];
    const float* W_b      = (const float*)d_in[8];
    const float* bn_gamma = (const float*)d_in[9];
    const float* bn_beta  = (const float*)d_in[10];
    const float* bn_mean  = (const float*)d_in[11];
    const float* bn_var   = (const float*)d_in[12];

    float* out = (float*)d_out;

    // Workspace layout: theta (B*N floats), then s (B floats)
    float* theta_buf = (float*)d_ws;
    float* s_buf     = (float*)((char*)d_ws + (size_t)Bn * Nn * sizeof(float));

    // zero the s accumulator each call (ws is NOT re-poisoned between replays)
    hipMemsetAsync(s_buf, 0, Bn * sizeof(float), stream);

    pass1_kernel<<<Bn * 18, 512, 0, stream>>>(
        x, g_w, g_b, theta_w, theta_b, phi_w, phi_b, theta_buf, s_buf);

    pass2_kernel<<<2048, 256, 0, stream>>>(
        x, theta_buf, s_buf, W_w, W_b, bn_gamma, bn_beta, bn_mean, bn_var, out);
}

// Round 4
// 77.069 us; speedup vs baseline: 1.4642x; 1.0779x over previous
//
#include <hip/hip_runtime.h>

// Problem constants (from reference): x is (B, C, H, W) fp32.
constexpr int Bn = 32;
constexpr int Cn = 256;
constexpr int Hn = 96;
constexpr int Wn = 48;
constexpr int Nn = Hn * Wn;       // 4608 spatial positions
constexpr int N4 = Nn / 4;        // 1152 float4 per (b,c) row
constexpr int TILES = 18;         // pass1 n4-tiles per batch (18*64 = 1152)
constexpr float BN_EPS = 1e-5f;

// native 4-float vector (HIP_vector_type is not accepted by the
// nontemporal builtins; this has identical 16B layout/alignment)
typedef float floatx4 __attribute__((ext_vector_type(4)));

// ---------------------------------------------------------------------------
// Pass 1: per (b, n) compute g/theta/phi channel dots over C.
//   Block = 512 threads = 8 waves; wave w covers channels [32w, 32w+32) for
//   the same 64 float4 n-positions; LDS reduction combines the 8 partials.
//   Grid = B * 18 blocks -> 4608 waves = 18/CU.
//   - theta[b,n] -> workspace
//   - per-block partial of sum_n phi*g -> part_out[b*18 + tile]
//     (deterministic: no atomics, no memset needed)
// ---------------------------------------------------------------------------
__global__ __launch_bounds__(512) void pass1_kernel(
    const float* __restrict__ x,
    const float* __restrict__ g_w, const float* __restrict__ g_b,
    const float* __restrict__ theta_w, const float* __restrict__ theta_b,
    const float* __restrict__ phi_w, const float* __restrict__ phi_b,
    float* __restrict__ theta_out,   // B * N floats
    float* __restrict__ part_out)    // B * 18 floats
{
    __shared__ float wg[Cn], wt[Cn], wp[Cn];
    __shared__ float4 red[3][8][64];   // 24 KiB cross-wave partials

    const int tid  = threadIdx.x;
    const int lane = tid & 63;
    const int wave = tid >> 6;

    if (tid < Cn) {
        wg[tid] = g_w[tid];
        wt[tid] = theta_w[tid];
        wp[tid] = phi_w[tid];
    }
    __syncthreads();

    const int bx   = blockIdx.x;
    const int b    = bx / TILES;
    const int tile = bx % TILES;
    const int n4   = tile * 64 + lane;   // 0..1151

    const float4* xb = reinterpret_cast<const float4*>(x)
                     + (size_t)b * (size_t)(Cn * N4) + n4;

    float4 ag = {0.f, 0.f, 0.f, 0.f};
    float4 at = {0.f, 0.f, 0.f, 0.f};
    float4 ap = {0.f, 0.f, 0.f, 0.f};

    const int c0 = wave * 32;
    #pragma unroll 8
    for (int cc = 0; cc < 32; ++cc) {
        const int c = c0 + cc;
        const float4 xv = xb[(size_t)c * N4];
        const float cg = wg[c], ct = wt[c], cp = wp[c];
        ag.x = fmaf(cg, xv.x, ag.x);
        ag.y = fmaf(cg, xv.y, ag.y);
        ag.z = fmaf(cg, xv.z, ag.z);
        ag.w = fmaf(cg, xv.w, ag.w);
        at.x = fmaf(ct, xv.x, at.x);
        at.y = fmaf(ct, xv.y, at.y);
        at.z = fmaf(ct, xv.z, at.z);
        at.w = fmaf(ct, xv.w, at.w);
        ap.x = fmaf(cp, xv.x, ap.x);
        ap.y = fmaf(cp, xv.y, ap.y);
        ap.z = fmaf(cp, xv.z, ap.z);
        ap.w = fmaf(cp, xv.w, ap.w);
    }

    red[0][wave][lane] = ag;
    red[1][wave][lane] = at;
    red[2][wave][lane] = ap;
    __syncthreads();

    if (wave == 0) {
        float4 sg = red[0][0][lane];
        float4 st = red[1][0][lane];
        float4 sp = red[2][0][lane];
        #pragma unroll
        for (int w = 1; w < 8; ++w) {
            const float4 rg = red[0][w][lane];
            const float4 rt = red[1][w][lane];
            const float4 rp = red[2][w][lane];
            sg.x += rg.x; sg.y += rg.y; sg.z += rg.z; sg.w += rg.w;
            st.x += rt.x; st.y += rt.y; st.z += rt.z; st.w += rt.w;
            sp.x += rp.x; sp.y += rp.y; sp.z += rp.z; sp.w += rp.w;
        }

        const float gb = g_b[0], tb = theta_b[0], pb = phi_b[0];

        // theta (store for pass 2) — keep cached, pass2 re-reads it
        float4 th;
        th.x = st.x + tb; th.y = st.y + tb; th.z = st.z + tb; th.w = st.w + tb;
        reinterpret_cast<float4*>(theta_out)[(size_t)b * N4 + n4] = th;

        // phi * g, 4 elements per lane
        float p = (sg.x + gb) * (sp.x + pb)
                + (sg.y + gb) * (sp.y + pb)
                + (sg.z + gb) * (sp.z + pb)
                + (sg.w + gb) * (sp.w + pb);

        // wave reduction over 64 lanes
        #pragma unroll
        for (int off = 32; off > 0; off >>= 1)
            p += __shfl_down(p, off);

        if (lane == 0)
            part_out[b * TILES + tile] = p;   // deterministic, no atomic
    }
}

// ---------------------------------------------------------------------------
// Pass 2: elementwise epilogue.
//   Grid = (36, B). Each block first reduces the 18 partials of its batch b
//   into s = (sum phi*g)/N, then processes 32 float4-iterations:
//   out = (theta[b,n] * s) * (W_w[c]*inv_std[c]) + bias_c + x      (nt store)
//   36 blocks * 256 threads = 9216 = 8 * N4  -> c advances by 8 per iter,
//   n4 is fixed per thread: no per-iteration div/mod.
// ---------------------------------------------------------------------------
__global__ __launch_bounds__(256) void pass2_kernel(
    const float* __restrict__ x,
    const float* __restrict__ theta_buf,
    const float* __restrict__ part_buf,
    const float* __restrict__ W_w, const float* __restrict__ W_b,
    const float* __restrict__ bn_gamma, const float* __restrict__ bn_beta,
    const float* __restrict__ bn_mean, const float* __restrict__ bn_var,
    float* __restrict__ out)
{
    __shared__ float s_sh;
    const int tid = threadIdx.x;
    const int b   = blockIdx.y;

    if (tid < 64) {   // wave 0 reduces the 18 per-tile partials
        float p = (tid < TILES) ? part_buf[b * TILES + tid] : 0.0f;
        #pragma unroll
        for (int off = 16; off > 0; off >>= 1)
            p += __shfl_down(p, off);
        if (tid == 0) s_sh = p * (1.0f / (float)Nn);
    }
    __syncthreads();
    const float sb = s_sh;

    const int tg  = blockIdx.x * 256 + tid;      // 0..9215
    const int c00 = tg / N4;                     // 0..7
    const int n4  = tg - c00 * N4;               // 0..1151

    const float4* xb  = reinterpret_cast<const float4*>(x)
                      + (size_t)b * (size_t)(Cn * N4);
    floatx4*      ob  = reinterpret_cast<floatx4*>(out)
                      + (size_t)b * (size_t)(Cn * N4);
    const float4  th  = reinterpret_cast<const float4*>(theta_buf)[(size_t)b * N4 + n4];
    const float   tsx = th.x * sb, tsy = th.y * sb,
                  tsz = th.z * sb, tsw = th.w * sb;

    #pragma unroll
    for (int it = 0; it < Cn / 8; ++it) {
        const int c = c00 + it * 8;
        const float inv_std = bn_gamma[c] * rsqrtf(bn_var[c] + BN_EPS);
        const float a = W_w[c] * inv_std;
        const float d = fmaf(W_b[c] - bn_mean[c], inv_std, bn_beta[c]);

        const size_t idx = (size_t)c * N4 + n4;
        const float4 xv = xb[idx];

        floatx4 o;
        o.x = fmaf(tsx, a, d) + xv.x;
        o.y = fmaf(tsy, a, d) + xv.y;
        o.z = fmaf(tsz, a, d) + xv.z;
        o.w = fmaf(tsw, a, d) + xv.w;

        // non-temporal: out is write-once, keep it out of L3 so x stays hot
        __builtin_nontemporal_store(o, &ob[idx]);
    }
}

extern "C" void kernel_launch(void* const* d_in, const int* in_sizes, int n_in,
                              void* d_out, int out_size, void* d_ws, size_t ws_size,
                              hipStream_t stream) {
    const float* x        = (const float*)d_in[0];
    const float* g_w      = (const float*)d_in[1];
    const float* g_b      = (const float*)d_in[2];
    const float* theta_w  = (const float*)d_in[3];
    const float* theta_b  = (const float*)d_in[4];
    const float* phi_w    = (const float*)d_in[5];
    const float* phi_b    = (const float*)d_in[6];
    const float* W_w      = (const float*)d_in[7];
    const float* W_b      = (const float*)d_in[8];
    const float* bn_gamma = (const float*)d_in[9];
    const float* bn_beta  = (const float*)d_in[10];
    const float* bn_mean  = (const float*)d_in[11];
    const float* bn_var   = (const float*)d_in[12];

    float* out = (float*)d_out;

    // Workspace layout: theta (B*N floats), then per-block partials (B*18)
    float* theta_buf = (float*)d_ws;
    float* part_buf  = (float*)((char*)d_ws + (size_t)Bn * Nn * sizeof(float));

    pass1_kernel<<<Bn * TILES, 512, 0, stream>>>(
        x, g_w, g_b, theta_w, theta_b, phi_w, phi_b, theta_buf, part_buf);

    dim3 g2(36, Bn);
    pass2_kernel<<<g2, 256, 0, stream>>>(
        x, theta_buf, part_buf, W_w, W_b, bn_gamma, bn_beta, bn_mean, bn_var, out);
}